// Round 1
// baseline (267.745 us; speedup 1.0000x reference)
//
#include <hip/hip_runtime.h>
#include <stdint.h>

// Problem constants (reference: N=2048, M=100000, D=128, K=5)
#define N_Q 2048
#define M_B 100000
#define D_DIM 128
#define KNN 5
#define SLAB 64                     // bank columns per staged slab
#define SLABS_TOTAL 1563            // ceil(M/64)
#define M_PAD (SLABS_TOTAL * 64)    // 100032
#define CHUNKS 32
#define SLABS_PER_CHUNK 49          // ceil(1563/32); last chunk has 44
#define ROWBLOCKS 16
#define TROWS 128                   // query rows per block
#define BIGF 3.0e38f

typedef __attribute__((ext_vector_type(8))) short short8;     // 8 bf16 = 4 VGPR (MFMA A/B frag)
typedef __attribute__((ext_vector_type(8))) unsigned short ushort8;
typedef __attribute__((ext_vector_type(4))) float f32x4;      // MFMA C/D frag

static __device__ __forceinline__ unsigned short f2bf(float f) {
  unsigned int u = __builtin_bit_cast(unsigned int, f);
  u = (u + 0x7FFFu + ((u >> 16) & 1u)) >> 16;   // round-to-nearest-even
  return (unsigned short)u;
}

// async global->LDS. LDS dest is wave-uniform base + lane*size (m104/m108):
// pass wave-uniform lds base, per-lane global ptr.
static __device__ __forceinline__ void gload_lds16(const void* g, void* l) {
  __builtin_amdgcn_global_load_lds((const __attribute__((address_space(1))) unsigned int*)g,
                                   (__attribute__((address_space(3))) unsigned int*)l, 16, 0, 0);
}
static __device__ __forceinline__ void gload_lds4(const void* g, void* l) {
  __builtin_amdgcn_global_load_lds((const __attribute__((address_space(1))) unsigned int*)g,
                                   (__attribute__((address_space(3))) unsigned int*)l, 4, 0, 0);
}

// ---------------------------------------------------------------------------
// K0: convert bank fp32 -> bf16 in slab-tiled kc-major layout, compute y2.
// Tiled layout: slab s, 16B unit u in [0,1024): u = kc*64 + j holds
// Y[s*64+j][kc*8 .. kc*8+8) as 8 bf16. So staging reads are contiguous 1KB
// per wave-instr and ds_read_b128 frag reads are bank-conflict-free.
// ---------------------------------------------------------------------------
__global__ __launch_bounds__(256) void k_prep(const float* __restrict__ Y,
                                              unsigned short* __restrict__ ybf,
                                              float* __restrict__ y2) {
  const int s = blockIdx.x;
  const int t = threadIdx.x;
  __shared__ float red[256];
  float ss = 0.f;
#pragma unroll
  for (int i = 0; i < 4; ++i) {
    const int u = i * 256 + t;          // j = u&63 == t&63 for all i
    const int j = u & 63;
    const int kc = u >> 6;              // = i*4 + (t>>6)
    int row = s * 64 + j;
    int rowc = (row < M_B) ? row : (M_B - 1);
    const float4* src = (const float4*)(Y + (size_t)rowc * D_DIM + kc * 8);
    float4 a = src[0];
    float4 b = src[1];
    ss += a.x * a.x + a.y * a.y + a.z * a.z + a.w * a.w
        + b.x * b.x + b.y * b.y + b.z * b.z + b.w * b.w;
    ushort8 o;
    o[0] = f2bf(a.x); o[1] = f2bf(a.y); o[2] = f2bf(a.z); o[3] = f2bf(a.w);
    o[4] = f2bf(b.x); o[5] = f2bf(b.y); o[6] = f2bf(b.z); o[7] = f2bf(b.w);
    *(ushort8*)(ybf + ((size_t)s * 1024 + (size_t)u) * 8) = o;   // coalesced 16B
  }
  red[t] = ss;
  __syncthreads();
  // threads t, t+64, t+128, t+192 all handled row j=t&63 (disjoint kc sets)
  if (t < 64) {
    const int row = s * 64 + t;
    const float tot = red[t] + red[t + 64] + red[t + 128] + red[t + 192];
    if (row < M_PAD) y2[row] = (row < M_B) ? tot : BIGF;   // pad cols pushed to +inf-ish
  }
}

// ---------------------------------------------------------------------------
// Main: block = 256 thr (4 waves). Block owns 128 query rows x one M-chunk.
// Wave w owns rows w*32 .. w*32+31 (2 row-tiles of 16). Per slab (64 cols):
// stage bf16 slab via global_load_lds, 32 MFMAs/wave, epilogue = d2 + top-5.
// MFMA layouts (verified m89/m91): A[m=lane&15][k=(lane>>4)*8+j],
// B[n=lane&15][k=(lane>>4)*8+j], C/D col=lane&15 row=(lane>>4)*4+reg.
// ---------------------------------------------------------------------------
__global__ __launch_bounds__(256, 2) void k_main(const float* __restrict__ X,
                                                 const unsigned short* __restrict__ ybf,
                                                 const float* __restrict__ y2,
                                                 float* __restrict__ part) {
  __shared__ __align__(16) char smem[41216];
  unsigned short* ys = (unsigned short*)smem;        // 16 KB slab (loop phase)
  float* y2s = (float*)(smem + 40960);               // 256 B y2 slab

  const int bid = blockIdx.x;
  // XCD swizzle: the 16 row-blocks of one chunk share bid&7 -> same XCD (heuristic)
  const int xcd = bid & 7;
  const int slot = bid >> 3;                         // 0..63
  const int chunk = xcd * 4 + (slot >> 4);           // 0..31
  const int rowblock = slot & 15;
  const int row0 = rowblock * TROWS;

  const int t = threadIdx.x;
  const int wave = t >> 6;
  const int lane = t & 63;
  const int lm = lane & 15;
  const int lq = lane >> 4;

  // ---- x2 for this block's 128 rows (fp32, exact), via LDS reduction ----
  float x2r[2][4];
  {
    float* red = (float*)smem;                       // 256 floats, pre-loop phase
    const int r = t >> 1, h = t & 1;
    const float4* xp = (const float4*)(X + (size_t)(row0 + r) * D_DIM + h * 64);
    float ss = 0.f;
#pragma unroll
    for (int i = 0; i < 16; ++i) {
      float4 v = xp[i];
      ss += v.x * v.x + v.y * v.y + v.z * v.z + v.w * v.w;
    }
    red[t] = ss;
    __syncthreads();
#pragma unroll
    for (int rt = 0; rt < 2; ++rt)
#pragma unroll
      for (int rr = 0; rr < 4; ++rr) {
        const int rl = wave * 32 + rt * 16 + lq * 4 + rr;  // accumulator row of this lane
        x2r[rt][rr] = red[rl * 2] + red[rl * 2 + 1];
      }
    __syncthreads();   // done with red before staging reuses smem
  }

  // ---- A fragments: X rows -> bf16, resident in registers for whole kernel ----
  short8 afrag[2][4];
#pragma unroll
  for (int rt = 0; rt < 2; ++rt)
#pragma unroll
    for (int ks = 0; ks < 4; ++ks) {
      const float* xr = X + (size_t)(row0 + wave * 32 + rt * 16 + lm) * D_DIM + ks * 32 + lq * 8;
      const float4 a = *(const float4*)xr;
      const float4 b = *(const float4*)(xr + 4);
      short8 f;
      f[0] = (short)f2bf(a.x); f[1] = (short)f2bf(a.y);
      f[2] = (short)f2bf(a.z); f[3] = (short)f2bf(a.w);
      f[4] = (short)f2bf(b.x); f[5] = (short)f2bf(b.y);
      f[6] = (short)f2bf(b.z); f[7] = (short)f2bf(b.w);
      afrag[rt][ks] = f;
    }

  // ---- per-lane streaming top-5 (squared distances), sorted ascending ----
  float top[2][4][5];
#pragma unroll
  for (int rt = 0; rt < 2; ++rt)
#pragma unroll
    for (int rr = 0; rr < 4; ++rr)
#pragma unroll
      for (int i = 0; i < 5; ++i) top[rt][rr][i] = BIGF;

  const int cs0 = chunk * SLABS_PER_CHUNK;
  const int nslab = (SLABS_TOTAL - cs0 < SLABS_PER_CHUNK) ? (SLABS_TOTAL - cs0) : SLABS_PER_CHUNK;

  for (int s = 0; s < nslab; ++s) {
    const int sg = cs0 + s;
    const unsigned short* src = ybf + (size_t)sg * 8192;
#pragma unroll
    for (int i = 0; i < 4; ++i) {
      const int ub = i * 256 + wave * 64;            // wave-uniform LDS unit base
      gload_lds16(src + (size_t)(ub + lane) * 8, ys + (size_t)ub * 8);
    }
    if (wave == 0) gload_lds4(y2 + (size_t)sg * 64 + lane, y2s);
    __syncthreads();   // compiler drains vmcnt before barrier

    f32x4 acc[2][4];
    const f32x4 zero = {0.f, 0.f, 0.f, 0.f};
#pragma unroll
    for (int rt = 0; rt < 2; ++rt)
#pragma unroll
      for (int ct = 0; ct < 4; ++ct) acc[rt][ct] = zero;

#pragma unroll
    for (int ct = 0; ct < 4; ++ct) {
      short8 bfr[4];
#pragma unroll
      for (int ks = 0; ks < 4; ++ks) {
        // unit = kc*64 + col, kc = ks*4+lq, col = ct*16+lm -> 256B contiguous per quad
        bfr[ks] = *(const short8*)(ys + (size_t)(((ks * 4 + lq) * 64 + ct * 16 + lm)) * 8);
      }
#pragma unroll
      for (int rt = 0; rt < 2; ++rt)
#pragma unroll
        for (int ks = 0; ks < 4; ++ks)
          acc[rt][ct] = __builtin_amdgcn_mfma_f32_16x16x32_bf16(afrag[rt][ks], bfr[ks],
                                                                acc[rt][ct], 0, 0, 0);
    }

    // ---- epilogue: d2 = x2 + y2 - 2*dot; compare-only fast path ----
    float y2c[4];
#pragma unroll
    for (int ct = 0; ct < 4; ++ct) y2c[ct] = y2s[ct * 16 + lm];
#pragma unroll
    for (int rt = 0; rt < 2; ++rt)
#pragma unroll
      for (int ct = 0; ct < 4; ++ct)
#pragma unroll
        for (int rr = 0; rr < 4; ++rr) {
          const float d2 = fmaf(-2.f, acc[rt][ct][rr], x2r[rt][rr] + y2c[ct]);
          if (d2 < top[rt][rr][4]) {                 // rare after warmup
            float m = d2;
            float n4 = fmaxf(top[rt][rr][3], m); m = fminf(top[rt][rr][3], m);
            float n3 = fmaxf(top[rt][rr][2], m); m = fminf(top[rt][rr][2], m);
            float n2 = fmaxf(top[rt][rr][1], m); m = fminf(top[rt][rr][1], m);
            float n1 = fmaxf(top[rt][rr][0], m); m = fminf(top[rt][rr][0], m);
            top[rt][rr][0] = m;  top[rt][rr][1] = n1; top[rt][rr][2] = n2;
            top[rt][rr][3] = n3; top[rt][rr][4] = n4;
          }
        }
    __syncthreads();   // WAR: all ds_reads done before next slab restages
  }

  // ---- merge 16 lanes x 5 per row -> block top-5 per row, write partials ----
  float* mg = (float*)smem;   // 128 rows x 80 floats = 40960 B (overlays ys, post-loop)
#pragma unroll
  for (int rt = 0; rt < 2; ++rt)
#pragma unroll
    for (int rr = 0; rr < 4; ++rr) {
      const int rl = wave * 32 + rt * 16 + lq * 4 + rr;
      float* dst = mg + rl * 80 + lm * 5;
#pragma unroll
      for (int i = 0; i < 5; ++i) dst[i] = top[rt][rr][i];
    }
  __syncthreads();
  if (t < TROWS) {
    const float* sp = mg + t * 80;
    float b0 = BIGF, b1 = BIGF, b2 = BIGF, b3 = BIGF, b4 = BIGF;
    for (int i = 0; i < 80; ++i) {
      const float v = sp[i];
      if (v < b4) {
        float m = v;
        float n4 = fmaxf(b3, m); m = fminf(b3, m);
        float n3 = fmaxf(b2, m); m = fminf(b2, m);
        float n2 = fmaxf(b1, m); m = fminf(b1, m);
        float n1 = fmaxf(b0, m); m = fminf(b0, m);
        b0 = m; b1 = n1; b2 = n2; b3 = n3; b4 = n4;
      }
    }
    float* pp = part + ((size_t)(row0 + t) * CHUNKS + chunk) * KNN;
    pp[0] = b0; pp[1] = b1; pp[2] = b2; pp[3] = b3; pp[4] = b4;
  }
}

// ---------------------------------------------------------------------------
// K2: per row merge 32 chunks x 5 partial d2 -> top-5, sqrt, mean, normalize
// ---------------------------------------------------------------------------
__global__ __launch_bounds__(256) void k_final(const float* __restrict__ part,
                                               const float* __restrict__ minp,
                                               const float* __restrict__ maxp,
                                               float* __restrict__ out) {
  const int row = blockIdx.x * 256 + threadIdx.x;
  if (row >= N_Q) return;
  const float* pp = part + (size_t)row * (CHUNKS * KNN);
  float b0 = BIGF, b1 = BIGF, b2 = BIGF, b3 = BIGF, b4 = BIGF;
  for (int i = 0; i < CHUNKS * KNN; ++i) {
    const float v = pp[i];
    if (v < b4) {
      float m = v;
      float n4 = fmaxf(b3, m); m = fminf(b3, m);
      float n3 = fmaxf(b2, m); m = fminf(b2, m);
      float n2 = fmaxf(b1, m); m = fminf(b1, m);
      float n1 = fmaxf(b0, m); m = fminf(b0, m);
      b0 = m; b1 = n1; b2 = n2; b3 = n3; b4 = n4;
    }
  }
  const float s = sqrtf(fmaxf(b0, 0.f)) + sqrtf(fmaxf(b1, 0.f)) + sqrtf(fmaxf(b2, 0.f))
                + sqrtf(fmaxf(b3, 0.f)) + sqrtf(fmaxf(b4, 0.f));
  const float mn = minp[0], mx = maxp[0];
  out[row] = (s * (1.0f / KNN) - mn) / (mx - mn);
}

extern "C" void kernel_launch(void* const* d_in, const int* in_sizes, int n_in,
                              void* d_out, int out_size, void* d_ws, size_t ws_size,
                              hipStream_t stream) {
  const float* X = (const float*)d_in[0];      // features (N,D) fp32
  const float* Y = (const float*)d_in[1];      // memory_bank (M,D) fp32
  const float* minp = (const float*)d_in[2];   // scalar
  const float* maxp = (const float*)d_in[3];   // scalar
  // d_in[4] = n_neighbors (K=5, hard-coded in the top-k machinery)
  float* out = (float*)d_out;

  char* ws = (char*)d_ws;
  const size_t ybf_bytes = (size_t)M_PAD * D_DIM * 2;         // 25,608,192
  const size_t y2_bytes = (size_t)M_PAD * 4;                  //    400,128
  unsigned short* ybf = (unsigned short*)ws;
  float* y2 = (float*)(ws + ybf_bytes);
  float* part = (float*)(ws + ybf_bytes + y2_bytes);          // N*32*5 fp32 = 1.25 MB

  k_prep<<<dim3(SLABS_TOTAL), dim3(256), 0, stream>>>(Y, ybf, y2);
  k_main<<<dim3(ROWBLOCKS * CHUNKS), dim3(256), 0, stream>>>(X, ybf, y2, part);
  k_final<<<dim3((N_Q + 255) / 256), dim3(256), 0, stream>>>(part, minp, maxp, out);
}

// Round 2
// 248.500 us; speedup vs baseline: 1.0774x; 1.0774x over previous
//
#include <hip/hip_runtime.h>
#include <stdint.h>

// Problem constants (reference: N=2048, M=100000, D=128, K=5)
#define N_Q 2048
#define M_B 100000
#define D_DIM 128
#define KNN 5
#define SLABS_TOTAL 1563            // ceil(M/64)
#define M_PAD (SLABS_TOTAL * 64)    // 100032
#define CHUNKS 64
#define SPC 25                      // ceil(1563/64); chunk 62 has 13, chunk 63 empty
#define ROWBLOCKS 16
#define TROWS 128
#define BIGF 3.0e38f
#define NEGF -3.0e38f
#define CAP 32                      // per-row-per-chunk candidate capacity (E[cnt]=5.6, P(>32)~1e-14)

typedef __attribute__((ext_vector_type(8))) short short8;     // MFMA A/B frag (8 bf16)
typedef __attribute__((ext_vector_type(4))) unsigned short ushort4v;
typedef __attribute__((ext_vector_type(4))) float f32x4;      // MFMA C/D frag

static __device__ __forceinline__ unsigned short f2bf(float f) {
  unsigned int u = __builtin_bit_cast(unsigned int, f);
  u = (u + 0x7FFFu + ((u >> 16) & 1u)) >> 16;   // RNE
  return (unsigned short)u;
}

static __device__ __forceinline__ void gload_lds16(const void* g, void* l) {
  __builtin_amdgcn_global_load_lds((const __attribute__((address_space(1))) unsigned int*)g,
                                   (__attribute__((address_space(3))) unsigned int*)l, 16, 0, 0);
}
static __device__ __forceinline__ void gload_lds4(const void* g, void* l) {
  __builtin_amdgcn_global_load_lds((const __attribute__((address_space(1))) unsigned int*)g,
                                   (__attribute__((address_space(3))) unsigned int*)l, 4, 0, 0);
}

// ---------------------------------------------------------------------------
// K0: bank fp32 -> bf16 slab-tiled (slab s, unit u=kc*64+j holds Y[s*64+j][kc*8..+8))
// plus ny2 = -0.5*|y|^2 (pads get NEGF). Fully coalesced flat reads:
// 16B-unit u16 = i*256+t over the 32KB slab; row=u16>>5, q=u16&31, kc=q>>1, half=q&1.
// ---------------------------------------------------------------------------
__global__ __launch_bounds__(256) void k_prep(const float* __restrict__ Y,
                                              unsigned short* __restrict__ ybf,
                                              float* __restrict__ ny2) {
  const int s = blockIdx.x;
  const int t = threadIdx.x;
  __shared__ float redy[64 * 33];                // +1 padded: bank = (row+slot)%32
#pragma unroll
  for (int i = 0; i < 8; ++i) {
    const int u = i * 256 + t;
    const int rowl = u >> 5;                     // 0..63
    const int q = u & 31;
    const int rowg = s * 64 + rowl;
    const int rowc = (rowg < M_B) ? rowg : (M_B - 1);
    const float4 v = ((const float4*)Y)[(size_t)rowc * 32 + q];
    redy[rowl * 33 + (t & 31)] = v.x * v.x + v.y * v.y + v.z * v.z + v.w * v.w;
    ushort4v o;
    o[0] = f2bf(v.x); o[1] = f2bf(v.y); o[2] = f2bf(v.z); o[3] = f2bf(v.w);
    const int unit = (q >> 1) * 64 + rowl;
    *(ushort4v*)(ybf + ((size_t)s * 1024 + unit) * 8 + (q & 1) * 4) = o;
  }
  __syncthreads();
  if (t < 64) {
    float sum = 0.f;
#pragma unroll
    for (int j = 0; j < 32; ++j) sum += redy[t * 33 + j];
    const int rowg = s * 64 + t;
    ny2[(size_t)s * 64 + t] = (rowg < M_B) ? (-0.5f * sum) : NEGF;
  }
}

// ---------------------------------------------------------------------------
// Main: block = 128 query rows x one M-chunk (~25 slabs of 64 cols).
// acc = dot - 0.5*(x2+y2)  =>  d2 = -2*acc; min-d2 == max-acc.
// PASS 1: MFMA + running per-lane max  -> per row T = 5th largest of 16 lane maxima.
// PASS 2: MFMA again, collect acc >= T into per-row LDS list (E[~6]/row), select 5.
// ---------------------------------------------------------------------------
__global__ __launch_bounds__(256, 4) void k_main(const float* __restrict__ X,
                                                 const unsigned short* __restrict__ ybf,
                                                 const float* __restrict__ ny2,
                                                 float* __restrict__ part) {
  __shared__ __align__(16) char smem[34560];
  unsigned short* ys = (unsigned short*)smem;        // 16384: bf16 slab
  float* ny2s = (float*)(smem + 16384);              //   256: -0.5*y2 slab
  float* lst = (float*)(smem + 16640);               // 16896: 128 x 33 (stride-padded)
  int* cnt = (int*)(smem + 33536);                   //   512
  float* Ts = (float*)(smem + 34048);                //   512: per-row acc-space threshold

  const int bid = blockIdx.x;
  const int xcd = bid & 7;                           // same chunk -> same XCD (L2 locality)
  const int idx = bid >> 3;                          // 0..127
  const int chunk = xcd * 8 + (idx & 7);             // 0..63
  const int rowblock = idx >> 3;                     // 0..15
  const int row0 = rowblock * TROWS;

  const int cs0 = chunk * SPC;
  int nslab = SLABS_TOTAL - cs0;
  if (nslab > SPC) nslab = SPC;

  const int t = threadIdx.x;
  const int wave = t >> 6;
  const int lane = t & 63;
  const int lm = lane & 15;
  const int lq = lane >> 4;

  if (nslab <= 0) {                                  // empty tail chunk: block-uniform
    if (t < TROWS) {
      float* pp = part + ((size_t)(row0 + t) * CHUNKS + chunk) * KNN;
#pragma unroll
      for (int i = 0; i < KNN; ++i) pp[i] = BIGF;
    }
    return;
  }

  // ---- nx2 = -0.5*|x|^2 for this lane's 8 accumulator rows (fp32 exact) ----
  float nx2r[2][4];
  {
    float* red = (float*)smem;                       // 1KB, pre-loop phase
    const int r = t >> 1, h = t & 1;
    const float4* xp = (const float4*)(X + (size_t)(row0 + r) * D_DIM + h * 64);
    float ss = 0.f;
#pragma unroll
    for (int i = 0; i < 16; ++i) {
      const float4 v = xp[i];
      ss += v.x * v.x + v.y * v.y + v.z * v.z + v.w * v.w;
    }
    red[t] = ss;
    __syncthreads();
#pragma unroll
    for (int rt = 0; rt < 2; ++rt)
#pragma unroll
      for (int rr = 0; rr < 4; ++rr) {
        const int rl = wave * 32 + rt * 16 + lq * 4 + rr;
        nx2r[rt][rr] = -0.5f * (red[rl * 2] + red[rl * 2 + 1]);
      }
    __syncthreads();
  }

  // ---- A fragments resident in registers (bf16) ----
  short8 afrag[2][4];
#pragma unroll
  for (int rt = 0; rt < 2; ++rt)
#pragma unroll
    for (int ks = 0; ks < 4; ++ks) {
      const float* xr = X + (size_t)(row0 + wave * 32 + rt * 16 + lm) * D_DIM + ks * 32 + lq * 8;
      const float4 a = *(const float4*)xr;
      const float4 b = *(const float4*)(xr + 4);
      short8 f;
      f[0] = (short)f2bf(a.x); f[1] = (short)f2bf(a.y);
      f[2] = (short)f2bf(a.z); f[3] = (short)f2bf(a.w);
      f[4] = (short)f2bf(b.x); f[5] = (short)f2bf(b.y);
      f[6] = (short)f2bf(b.z); f[7] = (short)f2bf(b.w);
      afrag[rt][ks] = f;
    }

  // =========================== PASS 1: lane maxima ===========================
  float runmax[2][4];
#pragma unroll
  for (int rt = 0; rt < 2; ++rt)
#pragma unroll
    for (int rr = 0; rr < 4; ++rr) runmax[rt][rr] = NEGF;

  for (int s = 0; s < nslab; ++s) {
    const int sg = cs0 + s;
    const unsigned short* src = ybf + (size_t)sg * 8192;
#pragma unroll
    for (int i = 0; i < 4; ++i) {
      const int ub = i * 256 + wave * 64;
      gload_lds16(src + (size_t)(ub + lane) * 8, ys + (size_t)ub * 8);
    }
    if (wave == 0) gload_lds4(ny2 + (size_t)sg * 64 + lane, ny2s);
    __syncthreads();

    float y2c[4];
#pragma unroll
    for (int ct = 0; ct < 4; ++ct) y2c[ct] = ny2s[ct * 16 + lm];

    f32x4 acc[2][4];
#pragma unroll
    for (int rt = 0; rt < 2; ++rt)
#pragma unroll
      for (int ct = 0; ct < 4; ++ct)
#pragma unroll
        for (int rr = 0; rr < 4; ++rr) acc[rt][ct][rr] = nx2r[rt][rr] + y2c[ct];

#pragma unroll
    for (int ct = 0; ct < 4; ++ct) {
      short8 bfr[4];
#pragma unroll
      for (int ks = 0; ks < 4; ++ks)
        bfr[ks] = *(const short8*)(ys + (size_t)(((ks * 4 + lq) * 64 + ct * 16 + lm)) * 8);
#pragma unroll
      for (int rt = 0; rt < 2; ++rt)
#pragma unroll
        for (int ks = 0; ks < 4; ++ks)
          acc[rt][ct] = __builtin_amdgcn_mfma_f32_16x16x32_bf16(afrag[rt][ks], bfr[ks],
                                                                acc[rt][ct], 0, 0, 0);
    }

#pragma unroll
    for (int rt = 0; rt < 2; ++rt)
#pragma unroll
      for (int rr = 0; rr < 4; ++rr) {
        const float mx = fmaxf(fmaxf(acc[rt][0][rr], acc[rt][1][rr]),
                               fmaxf(acc[rt][2][rr], acc[rt][3][rr]));
        runmax[rt][rr] = fmaxf(runmax[rt][rr], mx);
      }
    __syncthreads();   // WAR before restage
  }

  // ---- per row: T = 5th largest of 16 lane maxima (valid upper bound thr) ----
  {
    float* lmx = lst;                                // overlay (128 x 17 padded)
#pragma unroll
    for (int rt = 0; rt < 2; ++rt)
#pragma unroll
      for (int rr = 0; rr < 4; ++rr) {
        const int rl = wave * 32 + rt * 16 + lq * 4 + rr;
        lmx[rl * 17 + lm] = runmax[rt][rr];
      }
    __syncthreads();
    if (t < TROWS) {
      float b0 = NEGF, b1 = NEGF, b2 = NEGF, b3 = NEGF, b4 = NEGF;  // descending
      for (int i = 0; i < 16; ++i) {
        const float v = lmx[t * 17 + i];
        if (v > b4) {
          float m = v;
          float n3 = fminf(b3, m); m = fmaxf(b3, m);
          float n2 = fminf(b2, m); m = fmaxf(b2, m);
          float n1 = fminf(b1, m); m = fmaxf(b1, m);
          float n0 = fminf(b0, m); m = fmaxf(b0, m);
          b0 = m; b1 = n0; b2 = n1; b3 = n2; b4 = n3;
        }
      }
      Ts[t] = b4;
      cnt[t] = 0;
    }
    __syncthreads();   // lmx reads done; lst reuse is now safe
  }

  float tsr[2][4];
#pragma unroll
  for (int rt = 0; rt < 2; ++rt)
#pragma unroll
    for (int rr = 0; rr < 4; ++rr) tsr[rt][rr] = Ts[wave * 32 + rt * 16 + lq * 4 + rr];

  // =========================== PASS 2: collect ===============================
  for (int s = 0; s < nslab; ++s) {
    const int sg = cs0 + s;
    const unsigned short* src = ybf + (size_t)sg * 8192;
#pragma unroll
    for (int i = 0; i < 4; ++i) {
      const int ub = i * 256 + wave * 64;
      gload_lds16(src + (size_t)(ub + lane) * 8, ys + (size_t)ub * 8);
    }
    if (wave == 0) gload_lds4(ny2 + (size_t)sg * 64 + lane, ny2s);
    __syncthreads();

    float y2c[4];
#pragma unroll
    for (int ct = 0; ct < 4; ++ct) y2c[ct] = ny2s[ct * 16 + lm];

    f32x4 acc[2][4];
#pragma unroll
    for (int rt = 0; rt < 2; ++rt)
#pragma unroll
      for (int ct = 0; ct < 4; ++ct)
#pragma unroll
        for (int rr = 0; rr < 4; ++rr) acc[rt][ct][rr] = nx2r[rt][rr] + y2c[ct];

#pragma unroll
    for (int ct = 0; ct < 4; ++ct) {
      short8 bfr[4];
#pragma unroll
      for (int ks = 0; ks < 4; ++ks)
        bfr[ks] = *(const short8*)(ys + (size_t)(((ks * 4 + lq) * 64 + ct * 16 + lm)) * 8);
#pragma unroll
      for (int rt = 0; rt < 2; ++rt)
#pragma unroll
        for (int ks = 0; ks < 4; ++ks)
          acc[rt][ct] = __builtin_amdgcn_mfma_f32_16x16x32_bf16(afrag[rt][ks], bfr[ks],
                                                                acc[rt][ct], 0, 0, 0);
    }

#pragma unroll
    for (int rt = 0; rt < 2; ++rt)
#pragma unroll
      for (int rr = 0; rr < 4; ++rr) {
        const float mx = fmaxf(fmaxf(acc[rt][0][rr], acc[rt][1][rr]),
                               fmaxf(acc[rt][2][rr], acc[rt][3][rr]));
        if (__ballot(mx >= tsr[rt][rr])) {           // wave-uniform skip, ~20-60% taken
          const int rl = wave * 32 + rt * 16 + lq * 4 + rr;
#pragma unroll
          for (int ct = 0; ct < 4; ++ct) {
            const float a = acc[rt][ct][rr];
            if (a >= tsr[rt][rr]) {
              const int pos = atomicAdd(&cnt[rl], 1);
              if (pos < CAP) lst[rl * 33 + pos] = -2.f * a;   // d2
            }
          }
        }
      }
    __syncthreads();
  }

  // ---- per row: 5 smallest of ~6 collected candidates -> partials ----
  if (t < TROWS) {
    int c = cnt[t];
    if (c > CAP) c = CAP;
    float b0 = BIGF, b1 = BIGF, b2 = BIGF, b3 = BIGF, b4 = BIGF;  // ascending
    for (int i = 0; i < c; ++i) {
      const float v = lst[t * 33 + i];
      if (v < b4) {
        float m = v;
        float n3 = fmaxf(b3, m); m = fminf(b3, m);
        float n2 = fmaxf(b2, m); m = fminf(b2, m);
        float n1 = fmaxf(b1, m); m = fminf(b1, m);
        float n0 = fmaxf(b0, m); m = fminf(b0, m);
        b0 = m; b1 = n0; b2 = n1; b3 = n2; b4 = n3;
      }
    }
    float* pp = part + ((size_t)(row0 + t) * CHUNKS + chunk) * KNN;
    pp[0] = b0; pp[1] = b1; pp[2] = b2; pp[3] = b3; pp[4] = b4;
  }
}

// ---------------------------------------------------------------------------
// K2: per row merge 64 chunks x 5 partial d2 -> top-5, sqrt, mean, normalize
// ---------------------------------------------------------------------------
__global__ __launch_bounds__(256) void k_final(const float* __restrict__ part,
                                               const float* __restrict__ minp,
                                               const float* __restrict__ maxp,
                                               float* __restrict__ out) {
  const int row = blockIdx.x * 256 + threadIdx.x;
  if (row >= N_Q) return;
  const float4* pp = (const float4*)(part + (size_t)row * (CHUNKS * KNN));
  float b0 = BIGF, b1 = BIGF, b2 = BIGF, b3 = BIGF, b4 = BIGF;
  for (int i = 0; i < CHUNKS * KNN / 4; ++i) {
    const float4 q = pp[i];
#pragma unroll
    for (int j = 0; j < 4; ++j) {
      const float v = (j == 0) ? q.x : (j == 1) ? q.y : (j == 2) ? q.z : q.w;
      if (v < b4) {
        float m = v;
        float n3 = fmaxf(b3, m); m = fminf(b3, m);
        float n2 = fmaxf(b2, m); m = fminf(b2, m);
        float n1 = fmaxf(b1, m); m = fminf(b1, m);
        float n0 = fmaxf(b0, m); m = fminf(b0, m);
        b0 = m; b1 = n0; b2 = n1; b3 = n2; b4 = n3;
      }
    }
  }
  const float s = sqrtf(fmaxf(b0, 0.f)) + sqrtf(fmaxf(b1, 0.f)) + sqrtf(fmaxf(b2, 0.f))
                + sqrtf(fmaxf(b3, 0.f)) + sqrtf(fmaxf(b4, 0.f));
  const float mn = minp[0], mx = maxp[0];
  out[row] = (s * (1.0f / KNN) - mn) / (mx - mn);
}

extern "C" void kernel_launch(void* const* d_in, const int* in_sizes, int n_in,
                              void* d_out, int out_size, void* d_ws, size_t ws_size,
                              hipStream_t stream) {
  const float* X = (const float*)d_in[0];
  const float* Y = (const float*)d_in[1];
  const float* minp = (const float*)d_in[2];
  const float* maxp = (const float*)d_in[3];
  float* out = (float*)d_out;

  char* ws = (char*)d_ws;
  const size_t ybf_bytes = (size_t)M_PAD * D_DIM * 2;         // 25.6 MB
  const size_t ny2_bytes = (size_t)M_PAD * 4;                 // 400 KB
  unsigned short* ybf = (unsigned short*)ws;
  float* ny2 = (float*)(ws + ybf_bytes);
  float* part = (float*)(ws + ybf_bytes + ny2_bytes);         // 2048*64*5*4 = 2.62 MB

  k_prep<<<dim3(SLABS_TOTAL), dim3(256), 0, stream>>>(Y, ybf, ny2);
  k_main<<<dim3(ROWBLOCKS * CHUNKS), dim3(256), 0, stream>>>(X, ybf, ny2, part);
  k_final<<<dim3((N_Q + 255) / 256), dim3(256), 0, stream>>>(part, minp, maxp, out);
}